// Round 3
// baseline (148.193 us; speedup 1.0000x reference)
//
#include <hip/hip_runtime.h>
#include <math.h>

#define NB 8
#define NH 8
#define SEQ 512
#define DK 64
#define NC 5
#define D_IN 262144   // 8*512*64 per batch
#define OUT_SCORE (NB*NH*SEQ*SEQ)   // 16777216

typedef short short8 __attribute__((ext_vector_type(8)));
typedef float f32x16 __attribute__((ext_vector_type(16)));

// fp32 -> bf16 (RTNE), bit pattern in a short
__device__ __forceinline__ short f2bf(float f) {
  unsigned u = __float_as_uint(f);
  u += 0x7fffu + ((u >> 16) & 1u);
  return (short)(u >> 16);
}
__device__ __forceinline__ short8 pack8(float4 a, float4 b) {
  short8 r;
  r[0] = f2bf(a.x); r[1] = f2bf(a.y); r[2] = f2bf(a.z); r[3] = f2bf(a.w);
  r[4] = f2bf(b.x); r[5] = f2bf(b.y); r[6] = f2bf(b.z); r[7] = f2bf(b.w);
  return r;
}

// ---------------- Kernel A: ck[b][c] = sum_i K[b*D_IN+i] * Wp[i*5+c] ----------------
__global__ __launch_bounds__(256) void proj_kernel(const float* __restrict__ K,
                                                   const float* __restrict__ Wp,
                                                   float* __restrict__ ck) {
  int i4 = blockIdx.x * 256 + threadIdx.x;   // float4 index over D_IN
  const float4* Wp4 = (const float4*)Wp;
  float w[20];
#pragma unroll
  for (int t = 0; t < 5; ++t) {
    float4 v = Wp4[i4 * 5 + t];
    w[4*t+0] = v.x; w[4*t+1] = v.y; w[4*t+2] = v.z; w[4*t+3] = v.w;
  }
  float acc[NB][NC];
#pragma unroll
  for (int b = 0; b < NB; ++b)
#pragma unroll
    for (int c = 0; c < NC; ++c) acc[b][c] = 0.f;
#pragma unroll
  for (int b = 0; b < NB; ++b) {
    float4 kv = ((const float4*)(K + (size_t)b * D_IN))[i4];
    float ke[4] = {kv.x, kv.y, kv.z, kv.w};
#pragma unroll
    for (int e = 0; e < 4; ++e)
#pragma unroll
      for (int c = 0; c < NC; ++c)
        acc[b][c] = fmaf(ke[e], w[5*e + c], acc[b][c]);
  }

  __shared__ float red[4][NB * NC];
  int wave = threadIdx.x >> 6;
  int lane = threadIdx.x & 63;
#pragma unroll
  for (int bc = 0; bc < NB * NC; ++bc) {
    float v = acc[bc / NC][bc % NC];
#pragma unroll
    for (int off = 32; off > 0; off >>= 1) v += __shfl_down(v, off);
    if (lane == 0) red[wave][bc] = v;
  }
  __syncthreads();
  if (threadIdx.x < NB * NC) {
    float s = red[0][threadIdx.x] + red[1][threadIdx.x] +
              red[2][threadIdx.x] + red[3][threadIdx.x];
    atomicAdd(&ck[threadIdx.x], s);
  }
}

// ---------------- Kernel B: stats, loss, means ----------------
__global__ __launch_bounds__(256) void small_kernel(
    const float* __restrict__ K, const float* __restrict__ ck_raw,
    const float* __restrict__ bp, const float* __restrict__ Wq,
    const float* __restrict__ bq, const float* __restrict__ Wk,
    const float* __restrict__ bk, float* __restrict__ means,
    float* __restrict__ loss_out) {
  __shared__ float cq[NB][NC], ckk[NB][NC], ce_sh[NB];
  __shared__ int inds[NB];
  int t = threadIdx.x;
  if (t < NB) {
    float cp[NC], zq[NC], zk[NC];
#pragma unroll
    for (int c = 0; c < NC; ++c) cp[c] = ck_raw[t * NC + c] + bp[c];
#pragma unroll
    for (int c = 0; c < NC; ++c) { zq[c] = bq[c]; zk[c] = bk[c]; }
#pragma unroll
    for (int j = 0; j < NC; ++j)
#pragma unroll
      for (int c = 0; c < NC; ++c) {
        zq[c] = fmaf(cp[j], Wq[j * NC + c], zq[c]);
        zk[c] = fmaf(cp[j], Wk[j * NC + c], zk[c]);
      }
    float m = zq[0];
#pragma unroll
    for (int c = 1; c < NC; ++c) m = fmaxf(m, zq[c]);
    float e[NC], s = 0.f;
#pragma unroll
    for (int c = 0; c < NC; ++c) { e[c] = expf(zq[c] - m); s += e[c]; }
    float inv = 1.f / s;
    float p[NC];
#pragma unroll
    for (int c = 0; c < NC; ++c) { p[c] = e[c] * inv; cq[t][c] = p[c]; }
    int am = 0; float bv = p[0];
#pragma unroll
    for (int c = 1; c < NC; ++c) if (p[c] > bv) { bv = p[c]; am = c; }
    inds[t] = am;
    float se = 0.f;
#pragma unroll
    for (int c = 0; c < NC; ++c) se += expf(p[c] - bv);
    float lse = bv + logf(se);
    float ceb = 0.f;
#pragma unroll
    for (int c = 0; c < NC; ++c) ceb -= p[c] * (p[c] - lse);
    ce_sh[t] = ceb;
    m = zk[0];
#pragma unroll
    for (int c = 1; c < NC; ++c) m = fmaxf(m, zk[c]);
    s = 0.f;
#pragma unroll
    for (int c = 0; c < NC; ++c) { e[c] = expf(zk[c] - m); s += e[c]; }
    inv = 1.f / s;
#pragma unroll
    for (int c = 0; c < NC; ++c) ckk[t][c] = e[c] * inv;
  }
  __syncthreads();
  if (t == 0) {
    float mu[NC];
#pragma unroll
    for (int c = 0; c < NC; ++c) {
      float sm = 0.f;
      for (int b = 0; b < NB; ++b) sm += cq[b][c];
      mu[c] = sm * 0.125f;
    }
    float loss_lp = 0.f;
#pragma unroll
    for (int c = 0; c < NC; ++c) {
      float sm = 0.f;
      for (int b = 0; b < NB; ++b) sm += ckk[b][c];
      float mk = sm * 0.125f;
      float var = 0.f;
      for (int b = 0; b < NB; ++b) {
        float d = ckk[b][c] - mk;
        var += d * d;
      }
      var *= (1.f / 7.f);                 // ddof=1
      float sd = sqrtf(var);
      float sigma = log1pf(expf(sd));     // softplus
      float ls = logf(sigma);
      for (int b = 0; b < NB; ++b) {
        float z = (ckk[b][c] - mu[c]) / sigma;
        loss_lp += -0.5f * z * z - ls - 0.91893853320467274f;
      }
    }
    float ce = 0.f;
    for (int b = 0; b < NB; ++b) ce += ce_sh[b];
    ce *= 0.125f;
    loss_out[0] = -(loss_lp / 40.f) + ce;
  }
  __syncthreads();
  // means[c][j] = (1/8) * sum_{b: inds[b] != c+1} K[b*D_IN + j],  j<512
  for (int idx = t; idx < NC * 512; idx += 256) {
    int c = idx >> 9, j = idx & 511;
    float sm = 0.f;
#pragma unroll
    for (int b = 0; b < NB; ++b)
      if (inds[b] != c + 1) sm += K[(size_t)b * D_IN + j];
    means[idx] = sm * 0.125f;
  }
}

// ---------------- Kernel C: LDS-staged bf16-MFMA, A=K / B=Q (computes S^T frags) ----
// cm[b,h,c2,k,d] == means[(5h+c2)>>3, 64*(k&7)+d]; only {cmin,cmax} distinct.
// C/D mapping (HW-verified R2): col = lane&31, row = (reg&3)+8*(reg>>2)+4*(lane>>5).
// With A=K: row->k, col->q. Regs 4g..4g+3 are 4 consecutive k => float4 stores.
// qc: A-frag rows 0..7 = means[cmin], 8..15 = means[cmax], B = same Q frags.
//   Lane gets cmin at regs 0..3 (r=e+4hi), cmax at regs 4..7 => max, no shuffles.
#define LDSTRIDE 72   // shorts; 144 B: 16B-aligned rows, uniform b128 bank spread
__global__ __launch_bounds__(256) void score_kernel(const float* __restrict__ Q,
                                                    const float* __restrict__ K,
                                                    const float* __restrict__ means,
                                                    float* __restrict__ out) {
  __shared__ short Qs[128 * LDSTRIDE];
  __shared__ short Ks[128 * LDSTRIDE];

  const int bh = blockIdx.x;
  const int h  = bh & 7;
  const int qblk = blockIdx.y << 7;
  const int kblk = blockIdx.z << 7;
  const int tid = threadIdx.x;
  const int w = tid >> 6, lane = tid & 63;
  const int lo5 = lane & 31, hi = lane >> 5;
  const int wq = (w >> 1) << 6;   // wave's q offset in tile
  const int wk = (w & 1) << 6;    // wave's k offset in tile

  const float* Qg = Q + (size_t)bh * (SEQ * DK) + (size_t)qblk * DK;
  const float* Kg = K + (size_t)bh * (SEQ * DK) + (size_t)kblk * DK;

  // ---- stage both tiles (128 rows x 64 cols fp32 -> bf16), coalesced ----
#pragma unroll
  for (int i = 0; i < 4; ++i) {
    int f8 = i * 256 + tid;            // 8-float chunk id, 0..1023
    int row = f8 >> 3, c8 = f8 & 7;
    const float4* qp = (const float4*)(Qg + row * DK + c8 * 8);
    const float4* kp = (const float4*)(Kg + row * DK + c8 * 8);
    *(short8*)&Qs[row * LDSTRIDE + c8 * 8] = pack8(qp[0], qp[1]);
    *(short8*)&Ks[row * LDSTRIDE + c8 * 8] = pack8(kp[0], kp[1]);
  }

  // ---- means A-fragment (rows 0..7 cmin, 8..15 cmax, 16..31 zero) ----
  const int cmin = (5 * h) >> 3;
  const int cmax = (5 * h + 4) >> 3;
  short8 mfrag[4];
#pragma unroll
  for (int s = 0; s < 4; ++s) {
    float4 a = {0.f, 0.f, 0.f, 0.f}, b = {0.f, 0.f, 0.f, 0.f};
    if (lo5 < 16) {
      int c = (lo5 < 8) ? cmin : cmax;
      const float* mp = means + c * 512 + (lo5 & 7) * 64 + s * 16 + hi * 8;
      a = *(const float4*)mp;
      b = *(const float4*)(mp + 4);
    }
    mfrag[s] = pack8(a, b);
  }

  __syncthreads();

  f32x16 zero;
#pragma unroll
  for (int x = 0; x < 16; ++x) zero[x] = 0.f;

  const int fcol = hi * 16 + 0;  // byte offset within row handled below

  // ---- qc via MFMA (no shuffles) ----
  f32x16 aq0 = zero, aq1 = zero;
#pragma unroll
  for (int s = 0; s < 4; ++s) {
    short8 b0 = *(const short8*)&Qs[(wq + lo5)      * LDSTRIDE + s * 16 + hi * 8];
    short8 b1 = *(const short8*)&Qs[(wq + 32 + lo5) * LDSTRIDE + s * 16 + hi * 8];
    aq0 = __builtin_amdgcn_mfma_f32_32x32x16_bf16(mfrag[s], b0, aq0, 0, 0, 0);
    aq1 = __builtin_amdgcn_mfma_f32_32x32x16_bf16(mfrag[s], b1, aq1, 0, 0, 0);
  }
  float qcv[2][4];
#pragma unroll
  for (int e = 0; e < 4; ++e) {
    qcv[0][e] = fmaxf(aq0[e], aq0[4 + e]) * 0.125f;  // r = e + 4*hi
    qcv[1][e] = fmaxf(aq1[e], aq1[4 + e]) * 0.125f;
  }

  // ---- main: D[k][q] fragments ----
  f32x16 acc00 = zero, acc01 = zero, acc10 = zero, acc11 = zero;
#pragma unroll
  for (int s = 0; s < 4; ++s) {
    int co = s * 16 + hi * 8;
    short8 a0 = *(const short8*)&Ks[(wk + lo5)      * LDSTRIDE + co];
    short8 a1 = *(const short8*)&Ks[(wk + 32 + lo5) * LDSTRIDE + co];
    short8 b0 = *(const short8*)&Qs[(wq + lo5)      * LDSTRIDE + co];
    short8 b1 = *(const short8*)&Qs[(wq + 32 + lo5) * LDSTRIDE + co];
    acc00 = __builtin_amdgcn_mfma_f32_32x32x16_bf16(a0, b0, acc00, 0, 0, 0);
    acc01 = __builtin_amdgcn_mfma_f32_32x32x16_bf16(a0, b1, acc01, 0, 0, 0);
    acc10 = __builtin_amdgcn_mfma_f32_32x32x16_bf16(a1, b0, acc10, 0, 0, 0);
    acc11 = __builtin_amdgcn_mfma_f32_32x32x16_bf16(a1, b1, acc11, 0, 0, 0);
  }

  // ---- epilogue: float4 stores along k ----
  float* ob = out + (size_t)bh * (SEQ * SEQ);
  const int q0 = qblk + wq + lo5;
  const int q1 = q0 + 32;
  const int kb0 = kblk + wk + 4 * hi;
#pragma unroll
  for (int g = 0; g < 4; ++g) {
    float4 o00, o01, o10, o11;
    float* p00 = (float*)&o00; float* p01 = (float*)&o01;
    float* p10 = (float*)&o10; float* p11 = (float*)&o11;
#pragma unroll
    for (int e = 0; e < 4; ++e) {
      p00[e] = fmaxf(acc00[4 * g + e] * 0.125f, qcv[0][e]);
      p01[e] = fmaxf(acc01[4 * g + e] * 0.125f, qcv[1][e]);
      p10[e] = fmaxf(acc10[4 * g + e] * 0.125f, qcv[0][e]);
      p11[e] = fmaxf(acc11[4 * g + e] * 0.125f, qcv[1][e]);
    }
    *(float4*)(ob + (size_t)q0 * SEQ + kb0 + 8 * g)      = o00;
    *(float4*)(ob + (size_t)q1 * SEQ + kb0 + 8 * g)      = o01;
    *(float4*)(ob + (size_t)q0 * SEQ + kb0 + 32 + 8 * g) = o10;
    *(float4*)(ob + (size_t)q1 * SEQ + kb0 + 32 + 8 * g) = o11;
  }
}

extern "C" void kernel_launch(void* const* d_in, const int* in_sizes, int n_in,
                              void* d_out, int out_size, void* d_ws, size_t ws_size,
                              hipStream_t stream) {
  const float* Q  = (const float*)d_in[0];
  const float* K  = (const float*)d_in[1];
  const float* Wp = (const float*)d_in[2];
  const float* bp = (const float*)d_in[3];
  const float* Wq = (const float*)d_in[4];
  const float* bq = (const float*)d_in[5];
  const float* Wk = (const float*)d_in[6];
  const float* bk = (const float*)d_in[7];
  float* out = (float*)d_out;

  float* ck = (float*)d_ws;          // 64 floats (atomic accum)
  float* means = ck + 64;            // 5*512 floats

  hipMemsetAsync(ck, 0, NB * NC * sizeof(float), stream);
  proj_kernel<<<256, 256, 0, stream>>>(K, Wp, ck);
  small_kernel<<<1, 256, 0, stream>>>(K, ck, bp, Wq, bq, Wk, bk, means,
                                      out + OUT_SCORE);
  dim3 grid(64, 4, 4);
  score_kernel<<<grid, 256, 0, stream>>>(Q, K, means, out);
}

// Round 4
// 137.525 us; speedup vs baseline: 1.0776x; 1.0776x over previous
//
#include <hip/hip_runtime.h>
#include <math.h>

#define NB 8
#define NH 8
#define SEQ 512
#define DK 64
#define NC 5
#define D_IN 262144   // 8*512*64 per batch
#define OUT_SCORE (NB*NH*SEQ*SEQ)   // 16777216

typedef short short8 __attribute__((ext_vector_type(8)));
typedef float f32x16 __attribute__((ext_vector_type(16)));

// fp32 -> bf16 (RTNE), bit pattern in a short
__device__ __forceinline__ short f2bf(float f) {
  unsigned u = __float_as_uint(f);
  u += 0x7fffu + ((u >> 16) & 1u);
  return (short)(u >> 16);
}
__device__ __forceinline__ short8 pack8(float4 a, float4 b) {
  short8 r;
  r[0] = f2bf(a.x); r[1] = f2bf(a.y); r[2] = f2bf(a.z); r[3] = f2bf(a.w);
  r[4] = f2bf(b.x); r[5] = f2bf(b.y); r[6] = f2bf(b.z); r[7] = f2bf(b.w);
  return r;
}

// ---------------- Kernel A: ck[b][c] = sum_i K[b*D_IN+i] * Wp[i*5+c] ----------------
__global__ __launch_bounds__(256) void proj_kernel(const float* __restrict__ K,
                                                   const float* __restrict__ Wp,
                                                   float* __restrict__ ck) {
  int i4 = blockIdx.x * 256 + threadIdx.x;   // float4 index over D_IN
  const float4* Wp4 = (const float4*)Wp;
  float w[20];
#pragma unroll
  for (int t = 0; t < 5; ++t) {
    float4 v = Wp4[i4 * 5 + t];
    w[4*t+0] = v.x; w[4*t+1] = v.y; w[4*t+2] = v.z; w[4*t+3] = v.w;
  }
  float acc[NB][NC];
#pragma unroll
  for (int b = 0; b < NB; ++b)
#pragma unroll
    for (int c = 0; c < NC; ++c) acc[b][c] = 0.f;
#pragma unroll
  for (int b = 0; b < NB; ++b) {
    float4 kv = ((const float4*)(K + (size_t)b * D_IN))[i4];
    float ke[4] = {kv.x, kv.y, kv.z, kv.w};
#pragma unroll
    for (int e = 0; e < 4; ++e)
#pragma unroll
      for (int c = 0; c < NC; ++c)
        acc[b][c] = fmaf(ke[e], w[5*e + c], acc[b][c]);
  }

  __shared__ float red[4][NB * NC];
  int wave = threadIdx.x >> 6;
  int lane = threadIdx.x & 63;
#pragma unroll
  for (int bc = 0; bc < NB * NC; ++bc) {
    float v = acc[bc / NC][bc % NC];
#pragma unroll
    for (int off = 32; off > 0; off >>= 1) v += __shfl_down(v, off);
    if (lane == 0) red[wave][bc] = v;
  }
  __syncthreads();
  if (threadIdx.x < NB * NC) {
    float s = red[0][threadIdx.x] + red[1][threadIdx.x] +
              red[2][threadIdx.x] + red[3][threadIdx.x];
    atomicAdd(&ck[threadIdx.x], s);
  }
}

// ---------------- Kernel B: stats, loss, means ----------------
__global__ __launch_bounds__(256) void small_kernel(
    const float* __restrict__ K, const float* __restrict__ ck_raw,
    const float* __restrict__ bp, const float* __restrict__ Wq,
    const float* __restrict__ bq, const float* __restrict__ Wk,
    const float* __restrict__ bk, float* __restrict__ means,
    float* __restrict__ loss_out) {
  __shared__ float cq[NB][NC], ckk[NB][NC], ce_sh[NB];
  __shared__ int inds[NB];
  int t = threadIdx.x;
  if (t < NB) {
    float cp[NC], zq[NC], zk[NC];
#pragma unroll
    for (int c = 0; c < NC; ++c) cp[c] = ck_raw[t * NC + c] + bp[c];
#pragma unroll
    for (int c = 0; c < NC; ++c) { zq[c] = bq[c]; zk[c] = bk[c]; }
#pragma unroll
    for (int j = 0; j < NC; ++j)
#pragma unroll
      for (int c = 0; c < NC; ++c) {
        zq[c] = fmaf(cp[j], Wq[j * NC + c], zq[c]);
        zk[c] = fmaf(cp[j], Wk[j * NC + c], zk[c]);
      }
    float m = zq[0];
#pragma unroll
    for (int c = 1; c < NC; ++c) m = fmaxf(m, zq[c]);
    float e[NC], s = 0.f;
#pragma unroll
    for (int c = 0; c < NC; ++c) { e[c] = expf(zq[c] - m); s += e[c]; }
    float inv = 1.f / s;
    float p[NC];
#pragma unroll
    for (int c = 0; c < NC; ++c) { p[c] = e[c] * inv; cq[t][c] = p[c]; }
    int am = 0; float bv = p[0];
#pragma unroll
    for (int c = 1; c < NC; ++c) if (p[c] > bv) { bv = p[c]; am = c; }
    inds[t] = am;
    float se = 0.f;
#pragma unroll
    for (int c = 0; c < NC; ++c) se += expf(p[c] - bv);
    float lse = bv + logf(se);
    float ceb = 0.f;
#pragma unroll
    for (int c = 0; c < NC; ++c) ceb -= p[c] * (p[c] - lse);
    ce_sh[t] = ceb;
    m = zk[0];
#pragma unroll
    for (int c = 1; c < NC; ++c) m = fmaxf(m, zk[c]);
    s = 0.f;
#pragma unroll
    for (int c = 0; c < NC; ++c) { e[c] = expf(zk[c] - m); s += e[c]; }
    inv = 1.f / s;
#pragma unroll
    for (int c = 0; c < NC; ++c) ckk[t][c] = e[c] * inv;
  }
  __syncthreads();
  if (t == 0) {
    float mu[NC];
#pragma unroll
    for (int c = 0; c < NC; ++c) {
      float sm = 0.f;
      for (int b = 0; b < NB; ++b) sm += cq[b][c];
      mu[c] = sm * 0.125f;
    }
    float loss_lp = 0.f;
#pragma unroll
    for (int c = 0; c < NC; ++c) {
      float sm = 0.f;
      for (int b = 0; b < NB; ++b) sm += ckk[b][c];
      float mk = sm * 0.125f;
      float var = 0.f;
      for (int b = 0; b < NB; ++b) {
        float d = ckk[b][c] - mk;
        var += d * d;
      }
      var *= (1.f / 7.f);                 // ddof=1
      float sd = sqrtf(var);
      float sigma = log1pf(expf(sd));     // softplus
      float ls = logf(sigma);
      for (int b = 0; b < NB; ++b) {
        float z = (ckk[b][c] - mu[c]) / sigma;
        loss_lp += -0.5f * z * z - ls - 0.91893853320467274f;
      }
    }
    float ce = 0.f;
    for (int b = 0; b < NB; ++b) ce += ce_sh[b];
    ce *= 0.125f;
    loss_out[0] = -(loss_lp / 40.f) + ce;
  }
  __syncthreads();
  // means[c][j] = (1/8) * sum_{b: inds[b] != c+1} K[b*D_IN + j],  j<512
  for (int idx = t; idx < NC * 512; idx += 256) {
    int c = idx >> 9, j = idx & 511;
    float sm = 0.f;
#pragma unroll
    for (int b = 0; b < NB; ++b)
      if (inds[b] != c + 1) sm += K[(size_t)b * D_IN + j];
    means[idx] = sm * 0.125f;
  }
}

// ---------------- Kernel C: LDS-staged bf16-MFMA, A=Q / B=K => D[q][k] --------------
// cm[b,h,c2,k,d] == means[(5h+c2)>>3, 64*(k&7)+d]; only {cmin,cmax} distinct.
// C/D mapping (HW-verified): col = lane&31, row = (reg&3)+8*(reg>>2)+4*(lane>>5).
// col -> k (consecutive lanes = consecutive k): scalar stores give FULL 64B lines
// (each store inst covers rows {q,q+4} x 128B contiguous). This was R2's good store
// pattern; LDS staging is R3's good gather pattern. qc via means as B operand:
// cols 0..7 = cmin, 8..15 = cmax, gather with 2 shuffles/reg.
#define LDSTRIDE 72   // shorts; 144 B: 16B-aligned rows, uniform b128 bank spread
__global__ __launch_bounds__(256) void score_kernel(const float* __restrict__ Q,
                                                    const float* __restrict__ K,
                                                    const float* __restrict__ means,
                                                    float* __restrict__ out) {
  __shared__ short Qs[128 * LDSTRIDE];
  __shared__ short Ks[128 * LDSTRIDE];

  const int bh = blockIdx.x;
  const int h  = bh & 7;
  const int qblk = blockIdx.y << 7;
  const int kblk = blockIdx.z << 7;
  const int tid = threadIdx.x;
  const int w = tid >> 6, lane = tid & 63;
  const int lo5 = lane & 31, hi = lane >> 5;
  const int wq = (w >> 1) << 6;   // wave's q offset in tile
  const int wk = (w & 1) << 6;    // wave's k offset in tile

  const float* Qg = Q + (size_t)bh * (SEQ * DK) + (size_t)qblk * DK;
  const float* Kg = K + (size_t)bh * (SEQ * DK) + (size_t)kblk * DK;

  // ---- stage both tiles (128 rows x 64 cols fp32 -> bf16), coalesced ----
#pragma unroll
  for (int i = 0; i < 4; ++i) {
    int f8 = i * 256 + tid;            // 8-float chunk id, 0..1023
    int row = f8 >> 3, c8 = f8 & 7;
    const float4* qp = (const float4*)(Qg + row * DK + c8 * 8);
    const float4* kp = (const float4*)(Kg + row * DK + c8 * 8);
    *(short8*)&Qs[row * LDSTRIDE + c8 * 8] = pack8(qp[0], qp[1]);
    *(short8*)&Ks[row * LDSTRIDE + c8 * 8] = pack8(kp[0], kp[1]);
  }

  // ---- means B-fragment (cols 0..7 = cmin, 8..15 = cmax, 16..31 zero) ----
  const int cmin = (5 * h) >> 3;
  const int cmax = (5 * h + 4) >> 3;
  short8 mfrag[4];
#pragma unroll
  for (int s = 0; s < 4; ++s) {
    float4 a = {0.f, 0.f, 0.f, 0.f}, b = {0.f, 0.f, 0.f, 0.f};
    if (lo5 < 16) {
      int c = (lo5 < 8) ? cmin : cmax;
      const float* mp = means + c * 512 + (lo5 & 7) * 64 + s * 16 + hi * 8;
      a = *(const float4*)mp;
      b = *(const float4*)(mp + 4);
    }
    mfrag[s] = pack8(a, b);
  }

  __syncthreads();

  f32x16 zero;
#pragma unroll
  for (int x = 0; x < 16; ++x) zero[x] = 0.f;

  // ---- fused main + qc MFMA loop ----
  f32x16 acc00 = zero, acc01 = zero, acc10 = zero, acc11 = zero;
  f32x16 aq0 = zero, aq1 = zero;
#pragma unroll
  for (int s = 0; s < 4; ++s) {
    int co = s * 16 + hi * 8;
    short8 a0 = *(const short8*)&Qs[(wq + lo5)      * LDSTRIDE + co];
    short8 a1 = *(const short8*)&Qs[(wq + 32 + lo5) * LDSTRIDE + co];
    short8 b0 = *(const short8*)&Ks[(wk + lo5)      * LDSTRIDE + co];
    short8 b1 = *(const short8*)&Ks[(wk + 32 + lo5) * LDSTRIDE + co];
    acc00 = __builtin_amdgcn_mfma_f32_32x32x16_bf16(a0, b0, acc00, 0, 0, 0);
    acc01 = __builtin_amdgcn_mfma_f32_32x32x16_bf16(a0, b1, acc01, 0, 0, 0);
    acc10 = __builtin_amdgcn_mfma_f32_32x32x16_bf16(a1, b0, acc10, 0, 0, 0);
    acc11 = __builtin_amdgcn_mfma_f32_32x32x16_bf16(a1, b1, acc11, 0, 0, 0);
    aq0   = __builtin_amdgcn_mfma_f32_32x32x16_bf16(a0, mfrag[s], aq0, 0, 0, 0);
    aq1   = __builtin_amdgcn_mfma_f32_32x32x16_bf16(a1, mfrag[s], aq1, 0, 0, 0);
  }

  // ---- gather qc: lane needs max(col r, col r+8) at its own row set (same hi) ----
  float qcv0[16], qcv1[16];
  const int src0 = (hi << 5) + (lo5 & 7);
#pragma unroll
  for (int reg = 0; reg < 16; ++reg) {
    float m0 = fmaxf(__shfl(aq0[reg], src0), __shfl(aq0[reg], src0 + 8));
    float m1 = fmaxf(__shfl(aq1[reg], src0), __shfl(aq1[reg], src0 + 8));
    qcv0[reg] = m0 * 0.125f;
    qcv1[reg] = m1 * 0.125f;
  }

  // ---- epilogue: scalar stores, full-line coverage (lanes = consecutive k) ----
  float* ob = out + (size_t)bh * (SEQ * SEQ);
  const int kc0 = kblk + wk + lo5;
#pragma unroll
  for (int g = 0; g < 4; ++g) {
#pragma unroll
    for (int e = 0; e < 4; ++e) {
      int reg = 4 * g + e;
      int qrow = qblk + wq + e + 8 * g + 4 * hi;
      float q0 = qcv0[reg], q1 = qcv1[reg];
      __builtin_nontemporal_store(fmaxf(acc00[reg] * 0.125f, q0),
                                  ob + (size_t)qrow * SEQ + kc0);
      __builtin_nontemporal_store(fmaxf(acc01[reg] * 0.125f, q0),
                                  ob + (size_t)qrow * SEQ + kc0 + 32);
      __builtin_nontemporal_store(fmaxf(acc10[reg] * 0.125f, q1),
                                  ob + (size_t)(qrow + 32) * SEQ + kc0);
      __builtin_nontemporal_store(fmaxf(acc11[reg] * 0.125f, q1),
                                  ob + (size_t)(qrow + 32) * SEQ + kc0 + 32);
    }
  }
}

extern "C" void kernel_launch(void* const* d_in, const int* in_sizes, int n_in,
                              void* d_out, int out_size, void* d_ws, size_t ws_size,
                              hipStream_t stream) {
  const float* Q  = (const float*)d_in[0];
  const float* K  = (const float*)d_in[1];
  const float* Wp = (const float*)d_in[2];
  const float* bp = (const float*)d_in[3];
  const float* Wq = (const float*)d_in[4];
  const float* bq = (const float*)d_in[5];
  const float* Wk = (const float*)d_in[6];
  const float* bk = (const float*)d_in[7];
  float* out = (float*)d_out;

  float* ck = (float*)d_ws;          // 64 floats (atomic accum)
  float* means = ck + 64;            // 5*512 floats

  hipMemsetAsync(ck, 0, NB * NC * sizeof(float), stream);
  proj_kernel<<<256, 256, 0, stream>>>(K, Wp, ck);
  small_kernel<<<1, 256, 0, stream>>>(K, ck, bp, Wq, bq, Wk, bk, means,
                                      out + OUT_SCORE);
  dim3 grid(64, 4, 4);
  score_kernel<<<grid, 256, 0, stream>>>(Q, K, means, out);
}

// Round 5
// 130.949 us; speedup vs baseline: 1.1317x; 1.0502x over previous
//
#include <hip/hip_runtime.h>
#include <math.h>

#define NB 8
#define NH 8
#define SEQ 512
#define DK 64
#define NC 5
#define D_IN 262144   // 8*512*64 per batch
#define OUT_SCORE (NB*NH*SEQ*SEQ)   // 16777216
#define PROJ_BLOCKS 128

typedef short short8 __attribute__((ext_vector_type(8)));
typedef float f32x16 __attribute__((ext_vector_type(16)));

// fp32 -> bf16 (RTNE), bit pattern in a short
__device__ __forceinline__ short f2bf(float f) {
  unsigned u = __float_as_uint(f);
  u += 0x7fffu + ((u >> 16) & 1u);
  return (short)(u >> 16);
}
__device__ __forceinline__ short8 pack8(float4 a, float4 b) {
  short8 r;
  r[0] = f2bf(a.x); r[1] = f2bf(a.y); r[2] = f2bf(a.z); r[3] = f2bf(a.w);
  r[4] = f2bf(b.x); r[5] = f2bf(b.y); r[6] = f2bf(b.z); r[7] = f2bf(b.w);
  return r;
}

// ------- Kernel A: per-block partials of ck[b][c] = sum_i K[b,i]*Wp[i,c] -------
// 128 blocks x 256 threads; each thread handles 2 float4-chunks. No atomics.
__global__ __launch_bounds__(256) void proj_kernel(const float* __restrict__ K,
                                                   const float* __restrict__ Wp,
                                                   float* __restrict__ part) {
  const float4* Wp4 = (const float4*)Wp;
  float acc[NB][NC];
#pragma unroll
  for (int b = 0; b < NB; ++b)
#pragma unroll
    for (int c = 0; c < NC; ++c) acc[b][c] = 0.f;

#pragma unroll
  for (int it = 0; it < 2; ++it) {
    int i4 = blockIdx.x * 512 + it * 256 + threadIdx.x;  // float4 idx over D_IN
    float w[20];
#pragma unroll
    for (int t = 0; t < 5; ++t) {
      float4 v = Wp4[i4 * 5 + t];
      w[4*t+0] = v.x; w[4*t+1] = v.y; w[4*t+2] = v.z; w[4*t+3] = v.w;
    }
#pragma unroll
    for (int b = 0; b < NB; ++b) {
      float4 kv = ((const float4*)(K + (size_t)b * D_IN))[i4];
      float ke[4] = {kv.x, kv.y, kv.z, kv.w};
#pragma unroll
      for (int e = 0; e < 4; ++e)
#pragma unroll
        for (int c = 0; c < NC; ++c)
          acc[b][c] = fmaf(ke[e], w[5*e + c], acc[b][c]);
    }
  }

  __shared__ float red[4][NB * NC];
  int wave = threadIdx.x >> 6;
  int lane = threadIdx.x & 63;
#pragma unroll
  for (int bc = 0; bc < NB * NC; ++bc) {
    float v = acc[bc / NC][bc % NC];
#pragma unroll
    for (int off = 32; off > 0; off >>= 1) v += __shfl_down(v, off);
    if (lane == 0) red[wave][bc] = v;
  }
  __syncthreads();
  if (threadIdx.x < NB * NC)
    part[blockIdx.x * (NB * NC) + threadIdx.x] =
        red[0][threadIdx.x] + red[1][threadIdx.x] +
        red[2][threadIdx.x] + red[3][threadIdx.x];
}

// ---------------- Kernel B: reduce partials, stats, loss, means ----------------
__global__ __launch_bounds__(256) void small_kernel(
    const float* __restrict__ K, const float* __restrict__ part,
    const float* __restrict__ bp, const float* __restrict__ Wq,
    const float* __restrict__ bq, const float* __restrict__ Wk,
    const float* __restrict__ bk, float* __restrict__ means,
    float* __restrict__ loss_out) {
  __shared__ float colsum[NB * NC];
  __shared__ float cq[NB][NC], ckk[NB][NC], ce_sh[NB];
  __shared__ int inds[NB];
  int t = threadIdx.x;
  if (t < NB * NC) {
    float s = 0.f;
    for (int i = 0; i < PROJ_BLOCKS; ++i) s += part[i * (NB * NC) + t];
    colsum[t] = s;
  }
  __syncthreads();
  if (t < NB) {
    float cp[NC], zq[NC], zk[NC];
#pragma unroll
    for (int c = 0; c < NC; ++c) cp[c] = colsum[t * NC + c] + bp[c];
#pragma unroll
    for (int c = 0; c < NC; ++c) { zq[c] = bq[c]; zk[c] = bk[c]; }
#pragma unroll
    for (int j = 0; j < NC; ++j)
#pragma unroll
      for (int c = 0; c < NC; ++c) {
        zq[c] = fmaf(cp[j], Wq[j * NC + c], zq[c]);
        zk[c] = fmaf(cp[j], Wk[j * NC + c], zk[c]);
      }
    float m = zq[0];
#pragma unroll
    for (int c = 1; c < NC; ++c) m = fmaxf(m, zq[c]);
    float e[NC], s = 0.f;
#pragma unroll
    for (int c = 0; c < NC; ++c) { e[c] = expf(zq[c] - m); s += e[c]; }
    float inv = 1.f / s;
    float p[NC];
#pragma unroll
    for (int c = 0; c < NC; ++c) { p[c] = e[c] * inv; cq[t][c] = p[c]; }
    int am = 0; float bv = p[0];
#pragma unroll
    for (int c = 1; c < NC; ++c) if (p[c] > bv) { bv = p[c]; am = c; }
    inds[t] = am;
    float se = 0.f;
#pragma unroll
    for (int c = 0; c < NC; ++c) se += expf(p[c] - bv);
    float lse = bv + logf(se);
    float ceb = 0.f;
#pragma unroll
    for (int c = 0; c < NC; ++c) ceb -= p[c] * (p[c] - lse);
    ce_sh[t] = ceb;
    m = zk[0];
#pragma unroll
    for (int c = 1; c < NC; ++c) m = fmaxf(m, zk[c]);
    s = 0.f;
#pragma unroll
    for (int c = 0; c < NC; ++c) { e[c] = expf(zk[c] - m); s += e[c]; }
    inv = 1.f / s;
#pragma unroll
    for (int c = 0; c < NC; ++c) ckk[t][c] = e[c] * inv;
  }
  __syncthreads();
  if (t == 0) {
    float mu[NC];
#pragma unroll
    for (int c = 0; c < NC; ++c) {
      float sm = 0.f;
      for (int b = 0; b < NB; ++b) sm += cq[b][c];
      mu[c] = sm * 0.125f;
    }
    float loss_lp = 0.f;
#pragma unroll
    for (int c = 0; c < NC; ++c) {
      float sm = 0.f;
      for (int b = 0; b < NB; ++b) sm += ckk[b][c];
      float mk = sm * 0.125f;
      float var = 0.f;
      for (int b = 0; b < NB; ++b) {
        float d = ckk[b][c] - mk;
        var += d * d;
      }
      var *= (1.f / 7.f);                 // ddof=1
      float sd = sqrtf(var);
      float sigma = log1pf(expf(sd));     // softplus
      float ls = logf(sigma);
      for (int b = 0; b < NB; ++b) {
        float z = (ckk[b][c] - mu[c]) / sigma;
        loss_lp += -0.5f * z * z - ls - 0.91893853320467274f;
      }
    }
    float ce = 0.f;
    for (int b = 0; b < NB; ++b) ce += ce_sh[b];
    ce *= 0.125f;
    loss_out[0] = -(loss_lp / 40.f) + ce;
  }
  __syncthreads();
  // means[c][j] = (1/8) * sum_{b: inds[b] != c+1} K[b*D_IN + j],  j<512
  for (int idx = t; idx < NC * 512; idx += 256) {
    int c = idx >> 9, j = idx & 511;
    float sm = 0.f;
#pragma unroll
    for (int b = 0; b < NB; ++b)
      if (inds[b] != c + 1) sm += K[(size_t)b * D_IN + j];
    means[idx] = sm * 0.125f;
  }
}

// -------- Kernel C: LDS-staged bf16-MFMA, A=Q / B=K => D[q][k], col=k=lane --------
// cm[b,h,c2,k,d] == means[(5h+c2)>>3, 64*(k&7)+d]; only {cmin,cmax} distinct.
// C/D map (HW-verified): col=lane&31, row=(reg&3)+8*(reg>>2)+4*(lane>>5).
// qc (R3-verified construction): means as A (rows 0..7=cmin, 8..15=cmax),
//   Q-frags as B => lane holds qc[q=lo5][r=e+4hi] after in-lane fmax(reg e, reg 4+e).
//   Routed to store lanes via wave-private LDS (stride-10 pad), no shuffles, no barrier.
// Stores: plain (L2 write-back), scalar; each inst covers 2 rows x 128B = full lines.
#define LDSTRIDE 72   // shorts; 144 B rows: 16B-aligned, uniform b128 bank spread
__global__ __launch_bounds__(256) void score_kernel(const float* __restrict__ Q,
                                                    const float* __restrict__ K,
                                                    const float* __restrict__ means,
                                                    float* __restrict__ out) {
  __shared__ short Qs[128 * LDSTRIDE];
  __shared__ short Ks[128 * LDSTRIDE];
  __shared__ float qcbuf[4 * 64 * 10];   // [wave][q 0..63][r 0..7, pad 10]

  const int bh = blockIdx.x;
  const int h  = bh & 7;
  const int qblk = blockIdx.y << 7;
  const int kblk = blockIdx.z << 7;
  const int tid = threadIdx.x;
  const int w = tid >> 6, lane = tid & 63;
  const int lo5 = lane & 31, hi = lane >> 5;
  const int wq = (w >> 1) << 6;   // wave's q offset in tile
  const int wk = (w & 1) << 6;    // wave's k offset in tile

  const float* Qg = Q + (size_t)bh * (SEQ * DK) + (size_t)qblk * DK;
  const float* Kg = K + (size_t)bh * (SEQ * DK) + (size_t)kblk * DK;

  // ---- stage both tiles (128 rows x 64 cols fp32 -> bf16), coalesced ----
#pragma unroll
  for (int i = 0; i < 4; ++i) {
    int f8 = i * 256 + tid;            // 8-float chunk id, 0..1023
    int row = f8 >> 3, c8 = f8 & 7;
    const float4* qp = (const float4*)(Qg + row * DK + c8 * 8);
    const float4* kp = (const float4*)(Kg + row * DK + c8 * 8);
    *(short8*)&Qs[row * LDSTRIDE + c8 * 8] = pack8(qp[0], qp[1]);
    *(short8*)&Ks[row * LDSTRIDE + c8 * 8] = pack8(kp[0], kp[1]);
  }

  // ---- means A-fragment (rows 0..7 = cmin, 8..15 = cmax, 16..31 zero) ----
  const int cmin = (5 * h) >> 3;
  const int cmax = (5 * h + 4) >> 3;
  short8 mfrag[4];
#pragma unroll
  for (int s = 0; s < 4; ++s) {
    float4 a = {0.f, 0.f, 0.f, 0.f}, b = {0.f, 0.f, 0.f, 0.f};
    if (lo5 < 16) {
      int c = (lo5 < 8) ? cmin : cmax;
      const float* mp = means + c * 512 + (lo5 & 7) * 64 + s * 16 + hi * 8;
      a = *(const float4*)mp;
      b = *(const float4*)(mp + 4);
    }
    mfrag[s] = pack8(a, b);
  }

  __syncthreads();

  f32x16 zero;
#pragma unroll
  for (int x = 0; x < 16; ++x) zero[x] = 0.f;

  // ---- fused MFMA loop: main QK^T + qc (Q-frags reused as B for qc) ----
  f32x16 acc00 = zero, acc01 = zero, acc10 = zero, acc11 = zero;
  f32x16 aq0 = zero, aq1 = zero;
#pragma unroll
  for (int s = 0; s < 4; ++s) {
    int co = s * 16 + hi * 8;
    short8 a0 = *(const short8*)&Qs[(wq + lo5)      * LDSTRIDE + co];
    short8 a1 = *(const short8*)&Qs[(wq + 32 + lo5) * LDSTRIDE + co];
    short8 b0 = *(const short8*)&Ks[(wk + lo5)      * LDSTRIDE + co];
    short8 b1 = *(const short8*)&Ks[(wk + 32 + lo5) * LDSTRIDE + co];
    acc00 = __builtin_amdgcn_mfma_f32_32x32x16_bf16(a0, b0, acc00, 0, 0, 0);
    acc01 = __builtin_amdgcn_mfma_f32_32x32x16_bf16(a0, b1, acc01, 0, 0, 0);
    acc10 = __builtin_amdgcn_mfma_f32_32x32x16_bf16(a1, b0, acc10, 0, 0, 0);
    acc11 = __builtin_amdgcn_mfma_f32_32x32x16_bf16(a1, b1, acc11, 0, 0, 0);
    aq0   = __builtin_amdgcn_mfma_f32_32x32x16_bf16(mfrag[s], a0, aq0, 0, 0, 0);
    aq1   = __builtin_amdgcn_mfma_f32_32x32x16_bf16(mfrag[s], a1, aq1, 0, 0, 0);
  }

  // ---- in-lane qc extraction + wave-private LDS routing (no barrier needed) ----
  // aq: D[row=r or 8+r][col=q-in-wave]; lane holds q=lo5 (aq0) / 32+lo5 (aq1),
  // reg e -> (cmin, r=e+4hi), reg 4+e -> (cmax, same r).
  {
    int qb0 = w * 640 + lo5 * 10 + 4 * hi;
    float2 p;
    p.x = fmaxf(aq0[0], aq0[4]) * 0.125f;
    p.y = fmaxf(aq0[1], aq0[5]) * 0.125f;
    *(float2*)&qcbuf[qb0] = p;
    p.x = fmaxf(aq0[2], aq0[6]) * 0.125f;
    p.y = fmaxf(aq0[3], aq0[7]) * 0.125f;
    *(float2*)&qcbuf[qb0 + 2] = p;
    int qb1 = qb0 + 320;
    p.x = fmaxf(aq1[0], aq1[4]) * 0.125f;
    p.y = fmaxf(aq1[1], aq1[5]) * 0.125f;
    *(float2*)&qcbuf[qb1] = p;
    p.x = fmaxf(aq1[2], aq1[6]) * 0.125f;
    p.y = fmaxf(aq1[3], aq1[7]) * 0.125f;
    *(float2*)&qcbuf[qb1 + 2] = p;
  }

  // ---- epilogue: read qc from LDS (broadcast, conflict-free), plain stores ----
  float* ob = out + (size_t)bh * (SEQ * SEQ);
  const int kc0 = kblk + wk + lo5;
  const int r = lo5 & 7;
  const int qcb = w * 640 + r;
#pragma unroll
  for (int g = 0; g < 4; ++g) {
#pragma unroll
    for (int e = 0; e < 4; ++e) {
      int reg = 4 * g + e;
      int ql = e + 8 * g + 4 * hi;           // q within wave's 64-row window
      float qc0 = qcbuf[qcb + ql * 10];
      float qc1 = qcbuf[qcb + (ql + 32) * 10];
      int qrow = qblk + wq + ql;
      ob[(size_t)qrow * SEQ + kc0]             = fmaxf(acc00[reg] * 0.125f, qc0);
      ob[(size_t)qrow * SEQ + kc0 + 32]        = fmaxf(acc01[reg] * 0.125f, qc0);
      ob[(size_t)(qrow + 32) * SEQ + kc0]      = fmaxf(acc10[reg] * 0.125f, qc1);
      ob[(size_t)(qrow + 32) * SEQ + kc0 + 32] = fmaxf(acc11[reg] * 0.125f, qc1);
    }
  }
}

extern "C" void kernel_launch(void* const* d_in, const int* in_sizes, int n_in,
                              void* d_out, int out_size, void* d_ws, size_t ws_size,
                              hipStream_t stream) {
  const float* Q  = (const float*)d_in[0];
  const float* K  = (const float*)d_in[1];
  const float* Wp = (const float*)d_in[2];
  const float* bp = (const float*)d_in[3];
  const float* Wq = (const float*)d_in[4];
  const float* bq = (const float*)d_in[5];
  const float* Wk = (const float*)d_in[6];
  const float* bk = (const float*)d_in[7];
  float* out = (float*)d_out;

  float* part  = (float*)d_ws;             // 128*40 floats of partials
  float* means = part + 8192;              // 5*512 floats

  proj_kernel<<<PROJ_BLOCKS, 256, 0, stream>>>(K, Wp, part);
  small_kernel<<<1, 256, 0, stream>>>(K, part, bp, Wq, bq, Wk, bk, means,
                                      out + OUT_SCORE);
  dim3 grid(64, 4, 4);
  score_kernel<<<grid, 256, 0, stream>>>(Q, K, means, out);
}